// Round 19
// baseline (428.156 us; speedup 1.0000x reference)
//
#include <hip/hip_runtime.h>
#include <math.h>

#ifndef M_PI
#define M_PI 3.14159265358979323846
#endif

#define BB 4
#define TT 500
#define NSAMP 120000
#define NHARM 32
#define NFFT 256
#define NBIN 129
#define NHOPF 64
#define NFRAMES 1876
#define HID 64
#define MLPD 128
#define FEATD 88

#define R_MAG ((float)(500.0/1876.0))
#define R_UP_F ((float)(500.0/120000.0))

typedef float v2f __attribute__((ext_vector_type(2)));

// ---- workspace layout (float offsets) ----
#define OFF_HARML 0
#define OFF_HARMR 64000
#define OFF_AMP   128000
#define OFF_NMAGL 130000
#define OFF_NMAGR 388000
#define OFF_C1    646000
#define OFF_H1    646128
#define OFF_GI    (OFF_H1+256000)
#define OFF_GOUT  (OFF_GI+384000)
#define OFF_SPECL (OFF_GOUT+128000)
#define OFF_SPECR (OFF_SPECL+4*NFRAMES*258)
#define WS_END0   (OFF_SPECR+4*NFRAMES*258)     /* 5286160 */
/* transposed weights (k_prep) */
#define OFF_WT1   WS_END0
#define OFF_WT2   (OFF_WT1+11264)
#define OFF_WTIH  (OFF_WT2+16384)
#define OFF_WTPO  (OFF_WTIH+24576)
#define OFF_WTH   (OFF_WTPO+8192)
#define PREP_TOT (11264+16384+24576+8192+41344)

// f32 upsample position/interp chain, bit-exact to numpy float32 elementwise
__device__ __forceinline__ void up_coords(int m, int* i0, int* i1, float* w, float* w1){
  float pos = __fadd_rn(__fmul_rn(__fadd_rn((float)m, 0.5f), R_UP_F), -0.5f);
  pos = fminf(fmaxf(pos, 0.0f), 499.0f);
  int a = (int)pos;
  *i0 = a; *i1 = min(a+1, TT-1);
  float ww = __fsub_rn(pos, (float)a);
  *w = ww; *w1 = __fsub_rn(1.0f, ww);
}
__device__ __forceinline__ float f0_up_elem(const float* __restrict__ f0s, int m){
  int i0,i1; float w,w1;
  up_coords(m,&i0,&i1,&w,&w1);
  return __fadd_rn(__fmul_rn(f0s[i0], w1), __fmul_rn(f0s[i1], w));
}

// ---------------- one-time weight transpose to [in][out] ----------------
__global__ __launch_bounds__(256) void k_prep(const float* __restrict__ Wp1,
    const float* __restrict__ Wp2, const float* __restrict__ Wih,
    const float* __restrict__ Wpo, const float* __restrict__ WhL,
    const float* __restrict__ WhR, const float* __restrict__ Wam,
    const float* __restrict__ WnL, const float* __restrict__ WnR,
    float* __restrict__ ws){
  int idx = blockIdx.x*256 + threadIdx.x;
  if (idx >= PREP_TOT) return;
  if (idx < 11264){ int i = idx >> 7, c = idx & 127; ws[OFF_WT1 + idx] = Wp1[c*FEATD + i]; return; }
  idx -= 11264;
  if (idx < 16384){ int i = idx >> 7, c = idx & 127; ws[OFF_WT2 + idx] = Wp2[c*MLPD + i]; return; }
  idx -= 16384;
  if (idx < 24576){ int i = idx / 192, c = idx - i*192; ws[OFF_WTIH + idx] = Wih[c*MLPD + i]; return; }
  idx -= 24576;
  if (idx < 8192){ int i = idx >> 7, c = idx & 127; ws[OFF_WTPO + idx] = Wpo[c*HID + i]; return; }
  idx -= 8192;
  { int i = idx / 323, c = idx - i*323;
    float v;
    if (c < 32)       v = WhL[c*MLPD + i];
    else if (c < 64)  v = WhR[(c-32)*MLPD + i];
    else if (c == 64) v = Wam[i];
    else if (c < 194) v = WnL[(c-65)*MLPD + i];
    else              v = WnR[(c-194)*MLPD + i];
    ws[OFF_WTH + idx] = v; }
}

// ---------------- fused front: enc+pre1+pre2+gi, 10 rows/block ----------------
#define ROWS_F 10
__global__ __launch_bounds__(256) void k_front(const float* __restrict__ f0,
    const float* __restrict__ ldb, const float* __restrict__ vel,
    const float* __restrict__ bp1, const float* __restrict__ bp2,
    const float* __restrict__ bih, float* __restrict__ ws){
  int r0 = blockIdx.x * ROWS_F;
  int tid = threadIdx.x;
  __shared__ float norms[ROWS_F][4];
  __shared__ float feat[ROWS_F][FEATD];
  __shared__ float h1[ROWS_F][MLPD];
  __shared__ float h2[ROWS_F][MLPD];
  if (tid < ROWS_F){
    int row = r0 + tid; int b = row / TT;
    float f = f0[row];
    norms[tid][3] = (f > 0.0f) ? 1.0f : 0.0f;
    float fs = fmaxf(f, 20.0f);
    float fn = (logf(fs) - (float)2.995732273553991) / (float)5.5214609178622464;
    norms[tid][0] = fminf(fmaxf(fn, 0.0f), 1.0f);
    norms[tid][1] = fminf(fmaxf((ldb[row] + 80.0f) / 80.0f, 0.0f), 1.0f);
    norms[tid][2] = fminf(fmaxf(vel[b] / 7.0f, 0.0f), 1.0f);
  }
  __syncthreads();
  for (int idx = tid; idx < ROWS_F*FEATD; idx += 256){
    int r = idx / FEATD, e = idx - r*FEATD;
    float norm, g2 = 1.0f; int i;
    if (e < 64){ i = (e>>1)+1; norm = norms[r][0]; g2 = norms[r][3]; }
    else if (e < 80){ i = ((e-64)>>1)+1; norm = norms[r][1]; }
    else { i = ((e-80)>>1)+1; norm = norms[r][2]; }
    float ang = (float)M_PI * (float)i * norm;
    feat[r][e] = ((e & 1) ? cosf(ang) : sinf(ang)) * g2;
  }
  __syncthreads();
  {
    int c = tid & 127, rg = tid >> 7;
    const float* wt = ws + OFF_WT1;
    float acc[5];
    #pragma unroll
    for (int q=0;q<5;q++) acc[q] = bp1[c];
    for (int i=0;i<FEATD;i++){
      float w = wt[i*128 + c];
      #pragma unroll
      for (int q=0;q<5;q++) acc[q] = fmaf(feat[rg*5+q][i], w, acc[q]);
    }
    #pragma unroll
    for (int q=0;q<5;q++) h1[rg*5+q][c] = fmaxf(acc[q], 0.0f);
  }
  __syncthreads();
  {
    int c = tid & 127, rg = tid >> 7;
    const float* wt = ws + OFF_WT2;
    float acc[5];
    #pragma unroll
    for (int q=0;q<5;q++) acc[q] = bp2[c];
    for (int i=0;i<MLPD;i++){
      float w = wt[i*128 + c];
      #pragma unroll
      for (int q=0;q<5;q++) acc[q] = fmaf(h1[rg*5+q][i], w, acc[q]);
    }
    #pragma unroll
    for (int q=0;q<5;q++) h2[rg*5+q][c] = fmaxf(acc[q], 0.0f);
  }
  __syncthreads();
  if (tid < 192){
    const float* wt = ws + OFF_WTIH;
    float* gi = ws + OFF_GI;
    float acc[ROWS_F];
    #pragma unroll
    for (int r=0;r<ROWS_F;r++) acc[r] = bih[tid];
    for (int i=0;i<MLPD;i++){
      float w = wt[i*192 + tid];
      #pragma unroll
      for (int r=0;r<ROWS_F;r++) acc[r] = fmaf(h2[r][i], w, acc[r]);
    }
    #pragma unroll
    for (int r=0;r<ROWS_F;r++) gi[(size_t)(r0+r)*192 + tid] = acc[r];
  }
}

// numpy-exact pairwise block sum (leaf of the depth-10 perfect tree)
__device__ float np_block_sum(const float* __restrict__ f0s, int off, int n, float kf){
  float r[8];
  #pragma unroll
  for (int j=0;j<8;j++) r[j] = __fmul_rn(f0_up_elem(f0s, off+j), kf);
  int lim = n - (n & 7);
  int i = 8;
  for (; i<lim; i+=8){
    #pragma unroll
    for (int j=0;j<8;j++)
      r[j] = __fadd_rn(r[j], __fmul_rn(f0_up_elem(f0s, off+i+j), kf));
  }
  float res = __fadd_rn(__fadd_rn(__fadd_rn(r[0],r[1]), __fadd_rn(r[2],r[3])),
                        __fadd_rn(__fadd_rn(r[4],r[5]), __fadd_rn(r[6],r[7])));
  for (; i<n; i++)
    res = __fadd_rn(res, __fmul_rn(f0_up_elem(f0s, off+i), kf));
  return res;
}

// ---------------- fused mid: GRU + STFT + meanf0 ----------------
#define MID_GRU   BB
#define MID_MF    (MID_GRU + BB*32)
#define STFT_JOBS (2*BB*NFRAMES)
#define MID_STFT_BLOCKS ((STFT_JOBS+5)/6)
#define MID_BLOCKS (MID_MF + MID_STFT_BLOCKS)

#define CH  25
#define NCH 20

__device__ __forceinline__ float fsig(float x){
  return __fdividef(1.0f, 1.0f + __expf(-x));
}
__device__ __forceinline__ float ftanh(float x){
  return fmaf(-2.0f, __fdividef(1.0f, 1.0f + __expf(2.0f*x)), 1.0f);
}

// r19: h-broadcast via LDS (ds_read_b128, same addr across lanes =
// conflict-free broadcast; single-wave lgkm ordering, NO barrier) replaces
// 64 v_readlane/iter -- suspected serializer (~500-1000 cyc/iter; present
// in every slow variant r8-r18). hist[] already holds h(t) per step; step
// t+1 reads row (t-1)&63; row 63 zero-init for h(-1).
__global__
__attribute__((amdgpu_flat_work_group_size(384,384)))
__attribute__((amdgpu_waves_per_eu(1,4)))
void k_mid(
    const float* __restrict__ gi, const float* __restrict__ Whh,
    const float* __restrict__ bhh, float* __restrict__ gout,
    const float* __restrict__ f0, const float* __restrict__ nL,
    const float* __restrict__ nR, float* __restrict__ ws){
  __shared__ __align__(16) float sh[13696];
  int blk = blockIdx.x;
  int tid = threadIdx.x;

  if (blk < MID_GRU){
    float* gibuf = sh;            // [2][4800]
    float* hist  = sh + 9600;     // [64][64]
    int b = blk;
    int j = tid & 63;
    v2f wr2[32], wz2[32], wn2[32];
    float br=0.f, bz=0.f, bn=0.f;
    if (tid < 64){
      #pragma unroll
      for (int i=0;i<16;i++){
        float4 a = *(const float4*)(Whh + (size_t)(j)*64     + i*4);
        float4 c = *(const float4*)(Whh + (size_t)(64+j)*64  + i*4);
        float4 d = *(const float4*)(Whh + (size_t)(128+j)*64 + i*4);
        wr2[2*i] = (v2f){a.x, a.y}; wr2[2*i+1] = (v2f){a.z, a.w};
        wz2[2*i] = (v2f){c.x, c.y}; wz2[2*i+1] = (v2f){c.z, c.w};
        wn2[2*i] = (v2f){d.x, d.y}; wn2[2*i+1] = (v2f){d.z, d.w};
      }
      br = bhh[j]; bz = bhh[64+j]; bn = bhh[128+j];
      hist[63*64 + j] = 0.0f;     // h(-1) = 0
    }
    const float* gbase = gi + (size_t)b*TT*192;
    if (tid >= 64){
      int pt = tid - 64;
      for (int idx = pt; idx < CH*48; idx += 192){
        float4 v = *(const float4*)(gbase + idx*4);
        *(float4*)&gibuf[idx*4] = v;
      }
    }
    __syncthreads();
    float hreg = 0.0f;
    float* op = gout + (size_t)b*TT*64;
    for (int c=0; c<NCH; c++){
      if (tid >= 64){
        if (c+1 < NCH){
          int pt = tid - 64;
          const float* src = gbase + (size_t)(c+1)*CH*192;
          float* dst = &gibuf[((c+1)&1)*4800];
          for (int idx = pt; idx < CH*48; idx += 192){
            float4 v = *(const float4*)(src + idx*4);
            *(float4*)&dst[idx*4] = v;
          }
        }
      } else {
        const float* gch = &gibuf[(c&1)*4800];
        for (int tt=0; tt<CH; tt++){
          int t = c*CH + tt;
          float gr0 = gch[tt*192 + j];
          float gz0 = gch[tt*192 + 64 + j];
          float gn0 = gch[tt*192 + 128 + j];
          const float* hrow = &hist[((t+63)&63)<<6];   // h(t-1) broadcast
          v2f AR0={0.f,0.f}, AR1={0.f,0.f};
          v2f AZ0={0.f,0.f}, AZ1={0.f,0.f};
          v2f AN0={0.f,0.f}, AN1={0.f,0.f};
          #pragma unroll
          for (int q=0;q<16;q++){
            float4 h4 = *(const float4*)&hrow[4*q];
            v2f hA = (v2f){h4.x, h4.y};
            v2f hB = (v2f){h4.z, h4.w};
            AR0 = __builtin_elementwise_fma(wr2[2*q],   hA, AR0);
            AR1 = __builtin_elementwise_fma(wr2[2*q+1], hB, AR1);
            AZ0 = __builtin_elementwise_fma(wz2[2*q],   hA, AZ0);
            AZ1 = __builtin_elementwise_fma(wz2[2*q+1], hB, AZ1);
            AN0 = __builtin_elementwise_fma(wn2[2*q],   hA, AN0);
            AN1 = __builtin_elementwise_fma(wn2[2*q+1], hB, AN1);
          }
          float ar = __fadd_rn(__fadd_rn(AR0.x,AR0.y), __fadd_rn(AR1.x,AR1.y));
          float az = __fadd_rn(__fadd_rn(AZ0.x,AZ0.y), __fadd_rn(AZ1.x,AZ1.y));
          float an = __fadd_rn(__fadd_rn(AN0.x,AN0.y), __fadd_rn(AN1.x,AN1.y));
          float r = fsig(gr0 + ar + br);
          float z = fsig(gz0 + az + bz);
          float n = ftanh(gn0 + r*(an+bn));
          hreg = (1.0f - z)*n + z*hreg;
          int th = t & 63;
          hist[th*64 + j] = hreg;
          if (th == 63 || t == TT-1){
            int base_t = t - th;
            int per = th + 1;
            int nb = per >> 2;
            float* dst2 = op + base_t*64 + j*per;
            for (int q=0;q<nb;q++){
              float4 v = *(float4*)&hist[j*per + q*4];
              *(float4*)&dst2[q*4] = v;
            }
          }
        }
      }
      __syncthreads();
    }
  } else if (blk < MID_MF){
    int bk = blk - MID_GRU;
    int b = bk >> 5, k = bk & 31;
    float kf = (float)(k+1);
    float* f0s = sh;
    float* red = sh + 512;
    for (int i=tid;i<TT;i+=384) f0s[i] = f0[b*TT+i];
    __syncthreads();
    if (tid < 256){
      float lv[4];
      #pragma unroll
      for (int q=0;q<4;q++){
        int leafIdx = tid*4 + q;
        int off = 0, n = NSAMP;
        #pragma unroll
        for (int lvl=9; lvl>=0; --lvl){
          int n2 = (n>>1); n2 -= (n2 & 7);
          if ((leafIdx >> lvl) & 1){ off += n2; n -= n2; } else { n = n2; }
        }
        lv[q] = np_block_sum(f0s, off, n, kf);
      }
      red[tid] = __fadd_rn(__fadd_rn(lv[0],lv[1]), __fadd_rn(lv[2],lv[3]));
    }
    __syncthreads();
    for (int cnt=256; cnt>1; cnt>>=1){
      int half = cnt>>1;
      float v = 0.0f;
      if (tid < half) v = __fadd_rn(red[2*tid], red[2*tid+1]);
      __syncthreads();
      if (tid < half) red[tid] = v;
      __syncthreads();
    }
    if (tid==0){
      float mf = __fdiv_rn(red[0], 120000.0f);
      float c1 = __fmul_rn((float)(2.0*M_PI/48000.0), mf);
      ws[OFF_C1 + b*32 + k] = c1;
    }
  } else {
    int base = (blk - MID_MF)*6;
    int sub = tid >> 6;
    int j = tid & 63;
    float2* tw = (float2*)sh;
    float* frs = sh + 512 + sub*256;
    if (tid < 256){
      double a = (2.0*M_PI/256.0)*(double)tid;
      tw[tid] = make_float2((float)cos(a), (float)sin(a));
    }
    int jid = base + sub;
    bool act = jid < STFT_JOBS;
    int b=0, f=0; const float* x = nL;
    if (act){
      int ch = jid / (BB*NFRAMES);
      int rem = jid - ch*(BB*NFRAMES);
      b = rem / NFRAMES; f = rem - b*NFRAMES;
      x = (ch ? nR : nL) + (size_t)b*NSAMP;
      for (int n=j;n<256;n+=64){
        double a = (2.0*M_PI/256.0)*(double)n;
        int xi = f*NHOPF + n - 128;
        xi = xi < 0 ? -xi : xi;
        xi = xi >= NSAMP ? 2*(NSAMP-1)-xi : xi;
        float wnd = (float)(0.5 - 0.5*cos(a));
        frs[n] = x[xi]*wnd;
      }
    }
    __syncthreads();
    if (act){
      int ch = jid / (BB*NFRAMES);
      float* spec = ws + (ch ? OFF_SPECR : OFF_SPECL) + (size_t)(b*NFRAMES+f)*258;
      float re0=0.f, im0=0.f, re1=0.f, im1=0.f;
      int m0 = 0;
      #pragma unroll 4
      for (int n=0;n<256;n++){
        float fv = frs[n];
        int m1 = (m0 + ((n&3)<<6)) & 255;
        float2 t0 = tw[m0], t1 = tw[m1];
        re0 = fmaf(fv, t0.x, re0); im0 = fmaf(-fv, t0.y, im0);
        re1 = fmaf(fv, t1.x, re1); im1 = fmaf(-fv, t1.y, im1);
        m0 = (m0 + j) & 255;
      }
      float pq = frs[j] + frs[j+64] + frs[j+128] + frs[j+192];
      pq = (j & 1) ? -pq : pq;
      for (int o2=32;o2>0;o2>>=1) pq += __shfl_down(pq, o2, 64);
      spec[2*j]   = re0; spec[2*j+1]   = im0;
      spec[2*(j+64)] = re1; spec[2*(j+64)+1] = im1;
      if (j==0){ spec[256] = pq; spec[257] = 0.0f; }
    }
  }
}

// ---------------- fused post matmul + heads, 8 rows/block ----------------
#define ROWS_P 8
__global__ __launch_bounds__(384) void k_posthead(
  const float* __restrict__ bpo,
  const float* __restrict__ bhL, const float* __restrict__ bhR,
  const float* __restrict__ bam, const float* __restrict__ bnL,
  const float* __restrict__ bnR, float* __restrict__ ws){
  int r0 = blockIdx.x * ROWS_P;
  int tid = threadIdx.x;
  __shared__ float gs[ROWS_P][HID];
  __shared__ float post[ROWS_P][MLPD];
  const float* gout = ws + OFF_GOUT;
  for (int idx = tid; idx < ROWS_P*HID; idx += 384)
    gs[idx>>6][idx&63] = gout[(size_t)(r0 + (idx>>6))*HID + (idx&63)];
  __syncthreads();
  {
    int c = tid & 127, rg = tid >> 7;
    int rs = rg*3, nr = (rg==2)?2:3;
    const float* wt = ws + OFF_WTPO;
    float acc[3];
    for (int q=0;q<nr;q++) acc[q] = bpo[c];
    for (int i=0;i<HID;i++){
      float w = wt[i*128 + c];
      for (int q=0;q<nr;q++) acc[q] = fmaf(gs[rs+q][i], w, acc[q]);
    }
    for (int q=0;q<nr;q++) post[rs+q][c] = fmaxf(acc[q], 0.0f);
  }
  __syncthreads();
  if (tid < 323){
    int c = tid;
    const float* wt = ws + OFF_WTH;
    float bb; bool sp = false; float* o; int oc, ow;
    if (c < 32)      { bb=bhL[c];      o=ws+OFF_HARML; oc=c;     ow=32; }
    else if (c < 64) { bb=bhR[c-32];   o=ws+OFF_HARMR; oc=c-32;  ow=32; }
    else if (c == 64){ bb=bam[0];      o=ws+OFF_AMP;   oc=0;     ow=1; sp=true; }
    else if (c < 194){ bb=bnL[c-65];   o=ws+OFF_NMAGL; oc=c-65;  ow=129; }
    else             { bb=bnR[c-194];  o=ws+OFF_NMAGR; oc=c-194; ow=129; }
    float acc[ROWS_P];
    #pragma unroll
    for (int r=0;r<ROWS_P;r++) acc[r] = bb;
    for (int i=0;i<MLPD;i++){
      float w = wt[i*323 + c];
      #pragma unroll
      for (int r=0;r<ROWS_P;r++) acc[r] = fmaf(post[r][i], w, acc[r]);
    }
    #pragma unroll
    for (int r=0;r<ROWS_P;r++){
      float a = acc[r], v;
      if (sp) v = fmaxf(a, 0.0f) + log1pf(expf(-fabsf(a)));
      else    v = 1.0f/(1.0f+expf(-a));
      o[(size_t)(r0+r)*ow + oc] = v;
    }
  }
}

// ---------------- mag filter + irfft + window (IN-PLACE, rotation twiddle) ----
__global__ __launch_bounds__(256) void k_istft(float* __restrict__ ws){
  int fr = blockIdx.x;
  int ch = blockIdx.y;
  int b = fr / NFRAMES, f = fr - b*NFRAMES;
  float* spec = ws + (ch ? OFF_SPECR : OFF_SPECL) + (size_t)fr*258;
  const float* nmag = ws + (ch ? OFF_NMAGR : OFF_NMAGL) + (size_t)b*TT*NBIN;
  int t = threadIdx.x;
  __shared__ float2 mx[NBIN];
  double a = (2.0*M_PI/256.0)*(double)t;
  float cz = (float)cos(a), sz = (float)sin(a);
  if (t < NBIN){
    float pos = ((float)f + 0.5f) * R_MAG - 0.5f;
    pos = fminf(fmaxf(pos, 0.0f), 499.0f);
    int i0 = (int)pos, i1 = min(i0+1, TT-1);
    float w = pos - (float)i0;
    float mg = nmag[i0*NBIN + t]*(1.0f-w) + nmag[i1*NBIN + t]*w;
    mx[t] = make_float2(spec[2*t]*mg, spec[2*t+1]*mg);
  }
  __syncthreads();
  float acc0 = mx[0].x + ((t&1) ? -mx[128].x : mx[128].x);
  float acc = 0.0f;
  float c = cz, s = sz;
  #pragma unroll 4
  for (int k=1;k<128;k++){
    float2 v = mx[k];
    acc = fmaf(v.x, c, acc);
    acc = fmaf(-v.y, s, acc);
    float ts_ = s*sz, tc_ = c*sz;
    float cn = fmaf(c, cz, -ts_);
    float sn = fmaf(s, cz,  tc_);
    c = cn; s = sn;
  }
  float y = (acc0 + 2.0f*acc) * (1.0f/256.0f);
  float win = 0.5f - 0.5f*cz;
  spec[t] = y*win;
}

// ---------------- final: harmonic synth + OLA gather ----------------
__global__ __launch_bounds__(256) void k_out(const float* __restrict__ f0,
    const float* __restrict__ ws, float* __restrict__ out){
  __shared__ float win2[256];
  __shared__ float c1s[BB*32];
  {
    int t = threadIdx.x;
    double a = (2.0*M_PI/256.0)*(double)t;
    float w = (float)(0.5 - 0.5*cos(a));
    win2[t] = w*w;
    if (t < BB*32) c1s[t] = ws[OFF_C1 + t];
  }
  __syncthreads();
  int idx = blockIdx.x*256 + threadIdx.x;
  if (idx >= BB*2*NSAMP) return;
  int m = idx % NSAMP;
  int bc = idx / NSAMP;
  int ch = bc & 1, b = bc >> 1;
  int i0,i1; float w,w1;
  up_coords(m,&i0,&i1,&w,&w1);
  const float* f0b = f0 + b*TT;
  float f0u = __fadd_rn(__fmul_rn(f0b[i0], w1), __fmul_rn(f0b[i1], w));
  const float* am = ws + OFF_AMP + b*TT;
  float oa = __fadd_rn(__fmul_rn(am[i0], w1), __fmul_rn(am[i1], w));
  const float* ha = ws + (ch ? OFF_HARMR : OFF_HARML) + (size_t)b*TT*NHARM;
  float tm = (float)m;
  float hsum = 0.0f;
  for (int k=1;k<=NHARM;k++){
    float instf = __fmul_rn(f0u, (float)k);
    if (instf < 21600.0f){
      float a0 = ha[i0*NHARM + (k-1)], a1 = ha[i1*NHARM + (k-1)];
      float ak = __fadd_rn(__fmul_rn(a0, w1), __fmul_rn(a1, w));
      float ph = __fmul_rn(c1s[b*32 + (k-1)], tm);
      double rev = (double)ph * 0.15915494309189535;
      double fr2 = rev - floor(rev);
      float rad = (float)((fr2 - (fr2 >= 0.5 ? 1.0 : 0.0)) * 6.283185307179586);
      float s = sinf(rad);
      hsum = __fadd_rn(hsum, __fmul_rn(ak, s));
    }
  }
  float harm = __fmul_rn(hsum, oa);
  int p = m + 128;
  int fhi = min(p >> 6, NFRAMES-1);
  int flo = max((p - 192) >> 6, 0);
  const float* frb = ws + (ch ? OFF_SPECR : OFF_SPECL) + (size_t)b*NFRAMES*258;
  float nacc = 0.0f, wsum = 0.0f;
  for (int f=flo; f<=fhi; f++){
    int n = p - f*NHOPF;
    nacc += frb[f*258 + n];
    wsum += win2[n];
  }
  float noise = nacc / fmaxf(wsum, 1e-11f);
  out[idx] = __fadd_rn(harm, noise);
}

extern "C" void kernel_launch(void* const* d_in, const int* in_sizes, int n_in,
                              void* d_out, int out_size, void* d_ws, size_t ws_size,
                              hipStream_t stream){
  const float* f0  = (const float*)d_in[0];
  const float* ldb = (const float*)d_in[1];
  const float* vel = (const float*)d_in[2];
  const float* nL  = (const float*)d_in[3];
  const float* nR  = (const float*)d_in[4];
  const float* Wp1 = (const float*)d_in[5];
  const float* bp1 = (const float*)d_in[6];
  const float* Wp2 = (const float*)d_in[7];
  const float* bp2 = (const float*)d_in[8];
  const float* Wih = (const float*)d_in[9];
  const float* Whh = (const float*)d_in[10];
  const float* bih = (const float*)d_in[11];
  const float* bhh = (const float*)d_in[12];
  const float* Wpo = (const float*)d_in[13];
  const float* bpo = (const float*)d_in[14];
  const float* WhL = (const float*)d_in[15];
  const float* bhL = (const float*)d_in[16];
  const float* WhR = (const float*)d_in[17];
  const float* bhR = (const float*)d_in[18];
  const float* Wam = (const float*)d_in[19];
  const float* bam = (const float*)d_in[20];
  const float* WnL = (const float*)d_in[21];
  const float* bnL = (const float*)d_in[22];
  const float* WnR = (const float*)d_in[23];
  const float* bnR = (const float*)d_in[24];
  float* ws = (float*)d_ws;
  float* out = (float*)d_out;

  k_prep<<<(PREP_TOT+255)/256, 256, 0, stream>>>(Wp1, Wp2, Wih, Wpo, WhL, WhR, Wam, WnL, WnR, ws);
  k_front<<<BB*TT/ROWS_F, 256, 0, stream>>>(f0, ldb, vel, bp1, bp2, bih, ws);
  k_mid<<<MID_BLOCKS, 384, 0, stream>>>(ws+OFF_GI, Whh, bhh, ws+OFF_GOUT, f0, nL, nR, ws);
  k_posthead<<<BB*TT/ROWS_P, 384, 0, stream>>>(bpo, bhL, bhR, bam, bnL, bnR, ws);
  dim3 gs(BB*NFRAMES, 2);
  k_istft<<<gs, 256, 0, stream>>>(ws);
  k_out<<<(BB*2*NSAMP+255)/256, 256, 0, stream>>>(f0, ws, out);
}

// Round 20
// 384.194 us; speedup vs baseline: 1.1144x; 1.1144x over previous
//
#include <hip/hip_runtime.h>
#include <math.h>

#ifndef M_PI
#define M_PI 3.14159265358979323846
#endif

#define BB 4
#define TT 500
#define NSAMP 120000
#define NHARM 32
#define NFFT 256
#define NBIN 129
#define NHOPF 64
#define NFRAMES 1876
#define HID 64
#define MLPD 128
#define FEATD 88

#define R_MAG ((float)(500.0/1876.0))
#define R_UP_F ((float)(500.0/120000.0))

typedef float v2f __attribute__((ext_vector_type(2)));

// ---- workspace layout (float offsets) ----
#define OFF_HARML 0
#define OFF_HARMR 64000
#define OFF_AMP   128000
#define OFF_NMAGL 130000
#define OFF_NMAGR 388000
#define OFF_C1    646000
#define OFF_H1    646128
#define OFF_GI    (OFF_H1+256000)
#define OFF_GOUT  (OFF_GI+384000)
#define OFF_SPECL (OFF_GOUT+128000)
#define OFF_SPECR (OFF_SPECL+4*NFRAMES*258)
#define WS_END0   (OFF_SPECR+4*NFRAMES*258)     /* 5286160 */
/* transposed weights (k_prep) */
#define OFF_WT1   WS_END0
#define OFF_WT2   (OFF_WT1+11264)
#define OFF_WTIH  (OFF_WT2+16384)
#define OFF_WTPO  (OFF_WTIH+24576)
#define OFF_WTH   (OFF_WTPO+8192)
#define PREP_TOT (11264+16384+24576+8192+41344)

// f32 upsample position/interp chain, bit-exact to numpy float32 elementwise
__device__ __forceinline__ void up_coords(int m, int* i0, int* i1, float* w, float* w1){
  float pos = __fadd_rn(__fmul_rn(__fadd_rn((float)m, 0.5f), R_UP_F), -0.5f);
  pos = fminf(fmaxf(pos, 0.0f), 499.0f);
  int a = (int)pos;
  *i0 = a; *i1 = min(a+1, TT-1);
  float ww = __fsub_rn(pos, (float)a);
  *w = ww; *w1 = __fsub_rn(1.0f, ww);
}
__device__ __forceinline__ float f0_up_elem(const float* __restrict__ f0s, int m){
  int i0,i1; float w,w1;
  up_coords(m,&i0,&i1,&w,&w1);
  return __fadd_rn(__fmul_rn(f0s[i0], w1), __fmul_rn(f0s[i1], w));
}

// ---------------- one-time weight transpose to [in][out] ----------------
__global__ __launch_bounds__(256) void k_prep(const float* __restrict__ Wp1,
    const float* __restrict__ Wp2, const float* __restrict__ Wih,
    const float* __restrict__ Wpo, const float* __restrict__ WhL,
    const float* __restrict__ WhR, const float* __restrict__ Wam,
    const float* __restrict__ WnL, const float* __restrict__ WnR,
    float* __restrict__ ws){
  int idx = blockIdx.x*256 + threadIdx.x;
  if (idx >= PREP_TOT) return;
  if (idx < 11264){ int i = idx >> 7, c = idx & 127; ws[OFF_WT1 + idx] = Wp1[c*FEATD + i]; return; }
  idx -= 11264;
  if (idx < 16384){ int i = idx >> 7, c = idx & 127; ws[OFF_WT2 + idx] = Wp2[c*MLPD + i]; return; }
  idx -= 16384;
  if (idx < 24576){ int i = idx / 192, c = idx - i*192; ws[OFF_WTIH + idx] = Wih[c*MLPD + i]; return; }
  idx -= 24576;
  if (idx < 8192){ int i = idx >> 7, c = idx & 127; ws[OFF_WTPO + idx] = Wpo[c*HID + i]; return; }
  idx -= 8192;
  { int i = idx / 323, c = idx - i*323;
    float v;
    if (c < 32)       v = WhL[c*MLPD + i];
    else if (c < 64)  v = WhR[(c-32)*MLPD + i];
    else if (c == 64) v = Wam[i];
    else if (c < 194) v = WnL[(c-65)*MLPD + i];
    else              v = WnR[(c-194)*MLPD + i];
    ws[OFF_WTH + idx] = v; }
}

// ---------------- fused front: enc+pre1+pre2+gi, 10 rows/block ----------------
#define ROWS_F 10
__global__ __launch_bounds__(256) void k_front(const float* __restrict__ f0,
    const float* __restrict__ ldb, const float* __restrict__ vel,
    const float* __restrict__ bp1, const float* __restrict__ bp2,
    const float* __restrict__ bih, float* __restrict__ ws){
  int r0 = blockIdx.x * ROWS_F;
  int tid = threadIdx.x;
  __shared__ float norms[ROWS_F][4];
  __shared__ float feat[ROWS_F][FEATD];
  __shared__ float h1[ROWS_F][MLPD];
  __shared__ float h2[ROWS_F][MLPD];
  if (tid < ROWS_F){
    int row = r0 + tid; int b = row / TT;
    float f = f0[row];
    norms[tid][3] = (f > 0.0f) ? 1.0f : 0.0f;
    float fs = fmaxf(f, 20.0f);
    float fn = (logf(fs) - (float)2.995732273553991) / (float)5.5214609178622464;
    norms[tid][0] = fminf(fmaxf(fn, 0.0f), 1.0f);
    norms[tid][1] = fminf(fmaxf((ldb[row] + 80.0f) / 80.0f, 0.0f), 1.0f);
    norms[tid][2] = fminf(fmaxf(vel[b] / 7.0f, 0.0f), 1.0f);
  }
  __syncthreads();
  for (int idx = tid; idx < ROWS_F*FEATD; idx += 256){
    int r = idx / FEATD, e = idx - r*FEATD;
    float norm, g2 = 1.0f; int i;
    if (e < 64){ i = (e>>1)+1; norm = norms[r][0]; g2 = norms[r][3]; }
    else if (e < 80){ i = ((e-64)>>1)+1; norm = norms[r][1]; }
    else { i = ((e-80)>>1)+1; norm = norms[r][2]; }
    float ang = (float)M_PI * (float)i * norm;
    feat[r][e] = ((e & 1) ? cosf(ang) : sinf(ang)) * g2;
  }
  __syncthreads();
  {
    int c = tid & 127, rg = tid >> 7;
    const float* wt = ws + OFF_WT1;
    float acc[5];
    #pragma unroll
    for (int q=0;q<5;q++) acc[q] = bp1[c];
    for (int i=0;i<FEATD;i++){
      float w = wt[i*128 + c];
      #pragma unroll
      for (int q=0;q<5;q++) acc[q] = fmaf(feat[rg*5+q][i], w, acc[q]);
    }
    #pragma unroll
    for (int q=0;q<5;q++) h1[rg*5+q][c] = fmaxf(acc[q], 0.0f);
  }
  __syncthreads();
  {
    int c = tid & 127, rg = tid >> 7;
    const float* wt = ws + OFF_WT2;
    float acc[5];
    #pragma unroll
    for (int q=0;q<5;q++) acc[q] = bp2[c];
    for (int i=0;i<MLPD;i++){
      float w = wt[i*128 + c];
      #pragma unroll
      for (int q=0;q<5;q++) acc[q] = fmaf(h1[rg*5+q][i], w, acc[q]);
    }
    #pragma unroll
    for (int q=0;q<5;q++) h2[rg*5+q][c] = fmaxf(acc[q], 0.0f);
  }
  __syncthreads();
  if (tid < 192){
    const float* wt = ws + OFF_WTIH;
    float* gi = ws + OFF_GI;
    float acc[ROWS_F];
    #pragma unroll
    for (int r=0;r<ROWS_F;r++) acc[r] = bih[tid];
    for (int i=0;i<MLPD;i++){
      float w = wt[i*192 + tid];
      #pragma unroll
      for (int r=0;r<ROWS_F;r++) acc[r] = fmaf(h2[r][i], w, acc[r]);
    }
    #pragma unroll
    for (int r=0;r<ROWS_F;r++) gi[(size_t)(r0+r)*192 + tid] = acc[r];
  }
}

// numpy-exact pairwise block sum (leaf of the depth-10 perfect tree)
__device__ float np_block_sum(const float* __restrict__ f0s, int off, int n, float kf){
  float r[8];
  #pragma unroll
  for (int j=0;j<8;j++) r[j] = __fmul_rn(f0_up_elem(f0s, off+j), kf);
  int lim = n - (n & 7);
  int i = 8;
  for (; i<lim; i+=8){
    #pragma unroll
    for (int j=0;j<8;j++)
      r[j] = __fadd_rn(r[j], __fmul_rn(f0_up_elem(f0s, off+i+j), kf));
  }
  float res = __fadd_rn(__fadd_rn(__fadd_rn(r[0],r[1]), __fadd_rn(r[2],r[3])),
                        __fadd_rn(__fadd_rn(r[4],r[5]), __fadd_rn(r[6],r[7])));
  for (; i<n; i++)
    res = __fadd_rn(res, __fmul_rn(f0_up_elem(f0s, off+i), kf));
  return res;
}

// ---------------- fused mid: GRU + STFT + meanf0 ----------------
#define MID_GRU   BB
#define MID_MF    (MID_GRU + BB*32)
#define STFT_JOBS (2*BB*NFRAMES)
#define MID_STFT_BLOCKS ((STFT_JOBS+5)/6)
#define MID_BLOCKS (MID_MF + MID_STFT_BLOCKS)

#define RL(x,l) __uint_as_float(__builtin_amdgcn_readlane(__float_as_uint(x), (l)))

#define CH  25
#define NCH 20

__device__ __forceinline__ float fsig(float x){
  return __fdividef(1.0f, 1.0f + __expf(-x));
}
__device__ __forceinline__ float ftanh(float x){
  return fmaf(-2.0f, __fdividef(1.0f, 1.0f + __expf(2.0f*x)), 1.0f);
}

// GRU = r18's best measured variant (readlane h-broadcast + packed dot).
// r19 falsified the "readlane serializes" theory (LDS broadcast was SLOWER:
// +120cyc ds_read latency in the serial chain). ~508ns/iter is the floor
// across 9 structural variants -- consistent with DVFS-limited clocks when
// only 4 waves are active chip-wide (instruction-count cuts yield ~nothing).
__global__
__attribute__((amdgpu_flat_work_group_size(384,384)))
__attribute__((amdgpu_waves_per_eu(1,4)))
void k_mid(
    const float* __restrict__ gi, const float* __restrict__ Whh,
    const float* __restrict__ bhh, float* __restrict__ gout,
    const float* __restrict__ f0, const float* __restrict__ nL,
    const float* __restrict__ nR, float* __restrict__ ws){
  __shared__ __align__(16) float sh[13696];
  int blk = blockIdx.x;
  int tid = threadIdx.x;

  if (blk < MID_GRU){
    float* gibuf = sh;            // [2][4800]
    float* hist  = sh + 9600;     // [64][64]
    int b = blk;
    int j = tid & 63;
    v2f wr2[32], wz2[32], wn2[32];
    float br=0.f, bz=0.f, bn=0.f;
    if (tid < 64){
      #pragma unroll
      for (int i=0;i<16;i++){
        float4 a = *(const float4*)(Whh + (size_t)(j)*64     + i*4);
        float4 c = *(const float4*)(Whh + (size_t)(64+j)*64  + i*4);
        float4 d = *(const float4*)(Whh + (size_t)(128+j)*64 + i*4);
        wr2[2*i] = (v2f){a.x, a.y}; wr2[2*i+1] = (v2f){a.z, a.w};
        wz2[2*i] = (v2f){c.x, c.y}; wz2[2*i+1] = (v2f){c.z, c.w};
        wn2[2*i] = (v2f){d.x, d.y}; wn2[2*i+1] = (v2f){d.z, d.w};
      }
      br = bhh[j]; bz = bhh[64+j]; bn = bhh[128+j];
    }
    const float* gbase = gi + (size_t)b*TT*192;
    if (tid >= 64){
      int pt = tid - 64;
      for (int idx = pt; idx < CH*48; idx += 192){
        float4 v = *(const float4*)(gbase + idx*4);
        *(float4*)&gibuf[idx*4] = v;
      }
    }
    __syncthreads();
    float hreg = 0.0f;
    float* op = gout + (size_t)b*TT*64;
    for (int c=0; c<NCH; c++){
      if (tid >= 64){
        if (c+1 < NCH){
          int pt = tid - 64;
          const float* src = gbase + (size_t)(c+1)*CH*192;
          float* dst = &gibuf[((c+1)&1)*4800];
          for (int idx = pt; idx < CH*48; idx += 192){
            float4 v = *(const float4*)(src + idx*4);
            *(float4*)&dst[idx*4] = v;
          }
        }
      } else {
        const float* gch = &gibuf[(c&1)*4800];
        for (int tt=0; tt<CH; tt++){
          int t = c*CH + tt;
          float gr0 = gch[tt*192 + j];
          float gz0 = gch[tt*192 + 64 + j];
          float gn0 = gch[tt*192 + 128 + j];
          v2f AR0={0.f,0.f}, AR1={0.f,0.f};
          v2f AZ0={0.f,0.f}, AZ1={0.f,0.f};
          v2f AN0={0.f,0.f}, AN1={0.f,0.f};
          #pragma unroll
          for (int i=0;i<16;i++){
            v2f hA, hB;
            hA.x = RL(hreg, 2*i);    hA.y = RL(hreg, 2*i+1);
            hB.x = RL(hreg, 32+2*i); hB.y = RL(hreg, 33+2*i);
            AR0 = __builtin_elementwise_fma(wr2[i],    hA, AR0);
            AR1 = __builtin_elementwise_fma(wr2[16+i], hB, AR1);
            AZ0 = __builtin_elementwise_fma(wz2[i],    hA, AZ0);
            AZ1 = __builtin_elementwise_fma(wz2[16+i], hB, AZ1);
            AN0 = __builtin_elementwise_fma(wn2[i],    hA, AN0);
            AN1 = __builtin_elementwise_fma(wn2[16+i], hB, AN1);
          }
          float ar = __fadd_rn(__fadd_rn(AR0.x,AR0.y), __fadd_rn(AR1.x,AR1.y));
          float az = __fadd_rn(__fadd_rn(AZ0.x,AZ0.y), __fadd_rn(AZ1.x,AZ1.y));
          float an = __fadd_rn(__fadd_rn(AN0.x,AN0.y), __fadd_rn(AN1.x,AN1.y));
          float r = fsig(gr0 + ar + br);
          float z = fsig(gz0 + az + bz);
          float n = ftanh(gn0 + r*(an+bn));
          hreg = (1.0f - z)*n + z*hreg;
          int th = t & 63;
          hist[th*64 + j] = hreg;
          if (th == 63 || t == TT-1){
            int base_t = t - th;
            int per = th + 1;
            int nb = per >> 2;
            float* dst2 = op + base_t*64 + j*per;
            for (int q=0;q<nb;q++){
              float4 v = *(float4*)&hist[j*per + q*4];
              *(float4*)&dst2[q*4] = v;
            }
          }
        }
      }
      __syncthreads();
    }
  } else if (blk < MID_MF){
    int bk = blk - MID_GRU;
    int b = bk >> 5, k = bk & 31;
    float kf = (float)(k+1);
    float* f0s = sh;
    float* red = sh + 512;
    for (int i=tid;i<TT;i+=384) f0s[i] = f0[b*TT+i];
    __syncthreads();
    if (tid < 256){
      float lv[4];
      #pragma unroll
      for (int q=0;q<4;q++){
        int leafIdx = tid*4 + q;
        int off = 0, n = NSAMP;
        #pragma unroll
        for (int lvl=9; lvl>=0; --lvl){
          int n2 = (n>>1); n2 -= (n2 & 7);
          if ((leafIdx >> lvl) & 1){ off += n2; n -= n2; } else { n = n2; }
        }
        lv[q] = np_block_sum(f0s, off, n, kf);
      }
      red[tid] = __fadd_rn(__fadd_rn(lv[0],lv[1]), __fadd_rn(lv[2],lv[3]));
    }
    __syncthreads();
    for (int cnt=256; cnt>1; cnt>>=1){
      int half = cnt>>1;
      float v = 0.0f;
      if (tid < half) v = __fadd_rn(red[2*tid], red[2*tid+1]);
      __syncthreads();
      if (tid < half) red[tid] = v;
      __syncthreads();
    }
    if (tid==0){
      float mf = __fdiv_rn(red[0], 120000.0f);
      float c1 = __fmul_rn((float)(2.0*M_PI/48000.0), mf);
      ws[OFF_C1 + b*32 + k] = c1;
    }
  } else {
    int base = (blk - MID_MF)*6;
    int sub = tid >> 6;
    int j = tid & 63;
    float2* tw = (float2*)sh;
    float* frs = sh + 512 + sub*256;
    if (tid < 256){
      double a = (2.0*M_PI/256.0)*(double)tid;
      tw[tid] = make_float2((float)cos(a), (float)sin(a));
    }
    int jid = base + sub;
    bool act = jid < STFT_JOBS;
    int b=0, f=0; const float* x = nL;
    if (act){
      int ch = jid / (BB*NFRAMES);
      int rem = jid - ch*(BB*NFRAMES);
      b = rem / NFRAMES; f = rem - b*NFRAMES;
      x = (ch ? nR : nL) + (size_t)b*NSAMP;
      for (int n=j;n<256;n+=64){
        double a = (2.0*M_PI/256.0)*(double)n;
        int xi = f*NHOPF + n - 128;
        xi = xi < 0 ? -xi : xi;
        xi = xi >= NSAMP ? 2*(NSAMP-1)-xi : xi;
        float wnd = (float)(0.5 - 0.5*cos(a));
        frs[n] = x[xi]*wnd;
      }
    }
    __syncthreads();
    if (act){
      int ch = jid / (BB*NFRAMES);
      float* spec = ws + (ch ? OFF_SPECR : OFF_SPECL) + (size_t)(b*NFRAMES+f)*258;
      float re0=0.f, im0=0.f, re1=0.f, im1=0.f;
      int m0 = 0;
      #pragma unroll 4
      for (int n=0;n<256;n++){
        float fv = frs[n];
        int m1 = (m0 + ((n&3)<<6)) & 255;
        float2 t0 = tw[m0], t1 = tw[m1];
        re0 = fmaf(fv, t0.x, re0); im0 = fmaf(-fv, t0.y, im0);
        re1 = fmaf(fv, t1.x, re1); im1 = fmaf(-fv, t1.y, im1);
        m0 = (m0 + j) & 255;
      }
      float pq = frs[j] + frs[j+64] + frs[j+128] + frs[j+192];
      pq = (j & 1) ? -pq : pq;
      for (int o2=32;o2>0;o2>>=1) pq += __shfl_down(pq, o2, 64);
      spec[2*j]   = re0; spec[2*j+1]   = im0;
      spec[2*(j+64)] = re1; spec[2*(j+64)+1] = im1;
      if (j==0){ spec[256] = pq; spec[257] = 0.0f; }
    }
  }
}

// ---------------- fused post matmul + heads, 8 rows/block ----------------
#define ROWS_P 8
__global__ __launch_bounds__(384) void k_posthead(
  const float* __restrict__ bpo,
  const float* __restrict__ bhL, const float* __restrict__ bhR,
  const float* __restrict__ bam, const float* __restrict__ bnL,
  const float* __restrict__ bnR, float* __restrict__ ws){
  int r0 = blockIdx.x * ROWS_P;
  int tid = threadIdx.x;
  __shared__ float gs[ROWS_P][HID];
  __shared__ float post[ROWS_P][MLPD];
  const float* gout = ws + OFF_GOUT;
  for (int idx = tid; idx < ROWS_P*HID; idx += 384)
    gs[idx>>6][idx&63] = gout[(size_t)(r0 + (idx>>6))*HID + (idx&63)];
  __syncthreads();
  {
    int c = tid & 127, rg = tid >> 7;
    int rs = rg*3, nr = (rg==2)?2:3;
    const float* wt = ws + OFF_WTPO;
    float acc[3];
    for (int q=0;q<nr;q++) acc[q] = bpo[c];
    for (int i=0;i<HID;i++){
      float w = wt[i*128 + c];
      for (int q=0;q<nr;q++) acc[q] = fmaf(gs[rs+q][i], w, acc[q]);
    }
    for (int q=0;q<nr;q++) post[rs+q][c] = fmaxf(acc[q], 0.0f);
  }
  __syncthreads();
  if (tid < 323){
    int c = tid;
    const float* wt = ws + OFF_WTH;
    float bb; bool sp = false; float* o; int oc, ow;
    if (c < 32)      { bb=bhL[c];      o=ws+OFF_HARML; oc=c;     ow=32; }
    else if (c < 64) { bb=bhR[c-32];   o=ws+OFF_HARMR; oc=c-32;  ow=32; }
    else if (c == 64){ bb=bam[0];      o=ws+OFF_AMP;   oc=0;     ow=1; sp=true; }
    else if (c < 194){ bb=bnL[c-65];   o=ws+OFF_NMAGL; oc=c-65;  ow=129; }
    else             { bb=bnR[c-194];  o=ws+OFF_NMAGR; oc=c-194; ow=129; }
    float acc[ROWS_P];
    #pragma unroll
    for (int r=0;r<ROWS_P;r++) acc[r] = bb;
    for (int i=0;i<MLPD;i++){
      float w = wt[i*323 + c];
      #pragma unroll
      for (int r=0;r<ROWS_P;r++) acc[r] = fmaf(post[r][i], w, acc[r]);
    }
    #pragma unroll
    for (int r=0;r<ROWS_P;r++){
      float a = acc[r], v;
      if (sp) v = fmaxf(a, 0.0f) + log1pf(expf(-fabsf(a)));
      else    v = 1.0f/(1.0f+expf(-a));
      o[(size_t)(r0+r)*ow + oc] = v;
    }
  }
}

// ---------------- mag filter + irfft + window (IN-PLACE, even/odd split) ----
// cos(k(th+pi)) = (-1)^k cos(k th): samples t and t+128 share the even-k
// sum E(t) and odd-k sum O(t) (negated). Threads 0-127 compute E (rotation
// step 2th, 63 terms), threads 128-255 compute O (64 terms); combine via
// LDS: y(t)=(acc0+2(E+O))/256, y(t+128)=(acc0+2(E-O))/256. Per-thread work
// halves vs r18 (127 -> 63/64 rotation steps); drift also halves.
__global__ __launch_bounds__(256) void k_istft(float* __restrict__ ws){
  int fr = blockIdx.x;
  int ch = blockIdx.y;
  int b = fr / NFRAMES, f = fr - b*NFRAMES;
  float* spec = ws + (ch ? OFF_SPECR : OFF_SPECL) + (size_t)fr*258;
  const float* nmag = ws + (ch ? OFF_NMAGR : OFF_NMAGL) + (size_t)b*TT*NBIN;
  int tid = threadIdx.x;
  int t = tid & 127;
  bool oddk = tid >= 128;
  __shared__ float2 mx[NBIN];
  __shared__ float eo[256];
  double a = (2.0*M_PI/256.0)*(double)t;
  float cz = (float)cos(a), sz = (float)sin(a);
  if (tid < NBIN){
    float pos = ((float)f + 0.5f) * R_MAG - 0.5f;
    pos = fminf(fmaxf(pos, 0.0f), 499.0f);
    int i0 = (int)pos, i1 = min(i0+1, TT-1);
    float w = pos - (float)i0;
    float mg = nmag[i0*NBIN + tid]*(1.0f-w) + nmag[i1*NBIN + tid]*w;
    mx[tid] = make_float2(spec[2*tid]*mg, spec[2*tid+1]*mg);
  }
  __syncthreads();                    // all spec reads done -> in-place safe
  float c2 = fmaf(2.0f*cz, cz, -1.0f);   // cos(2th)
  float s2 = 2.0f*sz*cz;                 // sin(2th)
  float c, s; int k, nIter;
  if (!oddk){ c = c2; s = s2; k = 2; nIter = 63; }
  else      { c = cz; s = sz; k = 1; nIter = 64; }
  float acc = 0.0f;
  for (int it=0; it<nIter; ++it){
    float2 v = mx[k];                 // broadcast (k wave-uniform)
    acc = fmaf(v.x, c, acc);
    acc = fmaf(-v.y, s, acc);
    float cn = fmaf(c, c2, -s*s2);
    float sn = fmaf(s, c2,  c*s2);
    c = cn; s = sn;
    k += 2;
  }
  eo[tid] = acc;
  __syncthreads();
  float E = eo[t], O = eo[128+t];
  float acc0 = mx[0].x + ((t&1) ? -mx[128].x : mx[128].x);
  if (!oddk){
    float y = (acc0 + 2.0f*(E+O)) * (1.0f/256.0f);
    spec[t] = y * (0.5f - 0.5f*cz);
  } else {
    float y = (acc0 + 2.0f*(E-O)) * (1.0f/256.0f);
    spec[128+t] = y * (0.5f + 0.5f*cz);
  }
}

// ---------------- final: harmonic synth + OLA gather ----------------
__global__ __launch_bounds__(256) void k_out(const float* __restrict__ f0,
    const float* __restrict__ ws, float* __restrict__ out){
  __shared__ float win2[256];
  __shared__ float c1s[BB*32];
  {
    int t = threadIdx.x;
    double a = (2.0*M_PI/256.0)*(double)t;
    float w = (float)(0.5 - 0.5*cos(a));
    win2[t] = w*w;
    if (t < BB*32) c1s[t] = ws[OFF_C1 + t];
  }
  __syncthreads();
  int idx = blockIdx.x*256 + threadIdx.x;
  if (idx >= BB*2*NSAMP) return;
  int m = idx % NSAMP;
  int bc = idx / NSAMP;
  int ch = bc & 1, b = bc >> 1;
  int i0,i1; float w,w1;
  up_coords(m,&i0,&i1,&w,&w1);
  const float* f0b = f0 + b*TT;
  float f0u = __fadd_rn(__fmul_rn(f0b[i0], w1), __fmul_rn(f0b[i1], w));
  const float* am = ws + OFF_AMP + b*TT;
  float oa = __fadd_rn(__fmul_rn(am[i0], w1), __fmul_rn(am[i1], w));
  const float* ha = ws + (ch ? OFF_HARMR : OFF_HARML) + (size_t)b*TT*NHARM;
  float tm = (float)m;
  float hsum = 0.0f;
  for (int k=1;k<=NHARM;k++){
    float instf = __fmul_rn(f0u, (float)k);
    if (instf < 21600.0f){
      float a0 = ha[i0*NHARM + (k-1)], a1 = ha[i1*NHARM + (k-1)];
      float ak = __fadd_rn(__fmul_rn(a0, w1), __fmul_rn(a1, w));
      float ph = __fmul_rn(c1s[b*32 + (k-1)], tm);
      double rev = (double)ph * 0.15915494309189535;
      double fr2 = rev - floor(rev);
      float rad = (float)((fr2 - (fr2 >= 0.5 ? 1.0 : 0.0)) * 6.283185307179586);
      float s = sinf(rad);
      hsum = __fadd_rn(hsum, __fmul_rn(ak, s));
    }
  }
  float harm = __fmul_rn(hsum, oa);
  int p = m + 128;
  int fhi = min(p >> 6, NFRAMES-1);
  int flo = max((p - 192) >> 6, 0);
  const float* frb = ws + (ch ? OFF_SPECR : OFF_SPECL) + (size_t)b*NFRAMES*258;
  float nacc = 0.0f, wsum = 0.0f;
  for (int f=flo; f<=fhi; f++){
    int n = p - f*NHOPF;
    nacc += frb[f*258 + n];
    wsum += win2[n];
  }
  float noise = nacc / fmaxf(wsum, 1e-11f);
  out[idx] = __fadd_rn(harm, noise);
}

extern "C" void kernel_launch(void* const* d_in, const int* in_sizes, int n_in,
                              void* d_out, int out_size, void* d_ws, size_t ws_size,
                              hipStream_t stream){
  const float* f0  = (const float*)d_in[0];
  const float* ldb = (const float*)d_in[1];
  const float* vel = (const float*)d_in[2];
  const float* nL  = (const float*)d_in[3];
  const float* nR  = (const float*)d_in[4];
  const float* Wp1 = (const float*)d_in[5];
  const float* bp1 = (const float*)d_in[6];
  const float* Wp2 = (const float*)d_in[7];
  const float* bp2 = (const float*)d_in[8];
  const float* Wih = (const float*)d_in[9];
  const float* Whh = (const float*)d_in[10];
  const float* bih = (const float*)d_in[11];
  const float* bhh = (const float*)d_in[12];
  const float* Wpo = (const float*)d_in[13];
  const float* bpo = (const float*)d_in[14];
  const float* WhL = (const float*)d_in[15];
  const float* bhL = (const float*)d_in[16];
  const float* WhR = (const float*)d_in[17];
  const float* bhR = (const float*)d_in[18];
  const float* Wam = (const float*)d_in[19];
  const float* bam = (const float*)d_in[20];
  const float* WnL = (const float*)d_in[21];
  const float* bnL = (const float*)d_in[22];
  const float* WnR = (const float*)d_in[23];
  const float* bnR = (const float*)d_in[24];
  float* ws = (float*)d_ws;
  float* out = (float*)d_out;

  k_prep<<<(PREP_TOT+255)/256, 256, 0, stream>>>(Wp1, Wp2, Wih, Wpo, WhL, WhR, Wam, WnL, WnR, ws);
  k_front<<<BB*TT/ROWS_F, 256, 0, stream>>>(f0, ldb, vel, bp1, bp2, bih, ws);
  k_mid<<<MID_BLOCKS, 384, 0, stream>>>(ws+OFF_GI, Whh, bhh, ws+OFF_GOUT, f0, nL, nR, ws);
  k_posthead<<<BB*TT/ROWS_P, 384, 0, stream>>>(bpo, bhL, bhR, bam, bnL, bnR, ws);
  dim3 gs(BB*NFRAMES, 2);
  k_istft<<<gs, 256, 0, stream>>>(ws);
  k_out<<<(BB*2*NSAMP+255)/256, 256, 0, stream>>>(f0, ws, out);
}